// Round 7
// baseline (348.077 us; speedup 1.0000x reference)
//
#include <hip/hip_runtime.h>

typedef unsigned short u16;
typedef unsigned int u32;
typedef __attribute__((ext_vector_type(8))) short short8_t;
typedef __attribute__((ext_vector_type(4))) float f32x4;

#define HID 2048
#define KVH 512
#define NROW 4096   // B*S
#define SC2 0.18033688011112042f   // (1/sqrt(64)) * log2(e)

__device__ __forceinline__ u16 f2bf(float f){
  u32 u = __builtin_bit_cast(u32, f);
  u += 0x7fffu + ((u >> 16) & 1u);   // round-to-nearest-even
  return (u16)(u >> 16);
}
__device__ __forceinline__ u32 cvtpk_bf16(float lo, float hi){
  u32 r; asm("v_cvt_pk_bf16_f32 %0, %1, %2" : "=v"(r) : "v"(lo), "v"(hi)); return r;
}

union FragAB { short8_t v; uint4 u4; uint2 q[2]; };

__device__ __forceinline__ void gload_lds16(const u16* g, u16* l){
  __builtin_amdgcn_global_load_lds((const __attribute__((address_space(1))) void*)g,
                                   (__attribute__((address_space(3))) void*)l, 16, 0, 0);
}

// ---------- prep: fp32 -> bf16 convert ----------
__global__ __launch_bounds__(256)
void conv_bf16(const float* __restrict__ X, u16* __restrict__ Y, int n4)
{
  for (int i = blockIdx.x * 256 + threadIdx.x; i < n4; i += gridDim.x * 256) {
    float4 v = ((const float4*)X)[i];
    ushort4 h; h.x = f2bf(v.x); h.y = f2bf(v.y); h.z = f2bf(v.z); h.w = f2bf(v.w);
    ((ushort4*)Y)[i] = h;
  }
}

// ---------- prep: W[K][N] fp32 -> Wt[N][K] bf16 ----------
__global__ __launch_bounds__(256)
void transpose_conv(const float* __restrict__ W, u16* __restrict__ Wt, int K, int N)
{
  __shared__ float tile[32][33];
  int x = blockIdx.x * 32 + threadIdx.x;
  int y0 = blockIdx.y * 32;
  #pragma unroll
  for (int j = threadIdx.y; j < 32; j += 8)
    tile[j][threadIdx.x] = W[(size_t)(y0 + j) * N + x];
  __syncthreads();
  #pragma unroll
  for (int j = threadIdx.y; j < 32; j += 8)
    Wt[(size_t)(blockIdx.x * 32 + j) * K + y0 + threadIdx.x] = f2bf(tile[threadIdx.x][j]);
}

// two same-shape transposes in one launch (z selects)
__global__ __launch_bounds__(256)
void transpose_conv2(const float* __restrict__ W0, const float* __restrict__ W1,
                     u16* __restrict__ T0, u16* __restrict__ T1, int K, int N)
{
  __shared__ float tile[32][33];
  const float* W = blockIdx.z ? W1 : W0;
  u16* Wt = blockIdx.z ? T1 : T0;
  int x = blockIdx.x * 32 + threadIdx.x;
  int y0 = blockIdx.y * 32;
  #pragma unroll
  for (int j = threadIdx.y; j < 32; j += 8)
    tile[j][threadIdx.x] = W[(size_t)(y0 + j) * N + x];
  __syncthreads();
  #pragma unroll
  for (int j = threadIdx.y; j < 32; j += 8)
    Wt[(size_t)(blockIdx.x * 32 + j) * K + y0 + threadIdx.x] = f2bf(tile[threadIdx.x][j]);
}

// ---------- bf16 GEMM, B^T input (m97 structure) ----------
template<int CBF, int CT1>
__global__ __launch_bounds__(256)
void gemm_bt(const u16* __restrict__ A, const u16* __restrict__ B0,
             const u16* __restrict__ B1, void* __restrict__ C0,
             void* __restrict__ C1, int nsplit, int N, int K, float scale)
{
  __shared__ __align__(16) u16 As[128 * 64];
  __shared__ __align__(16) u16 Bs[128 * 64];
  const int t = threadIdx.x, lane = t & 63, wid = t >> 6;
  const int wm = wid >> 1, wn = wid & 1;
  const int r = lane & 15, g = lane >> 4;
  const u16* Bt; char* Cp; int n0;
  if ((int)blockIdx.x < nsplit) { Bt = B0; Cp = (char*)C0; n0 = blockIdx.x * 128; }
  else { Bt = B1; Cp = (char*)C1; n0 = ((int)blockIdx.x - nsplit) * 128; }
  const int m0 = blockIdx.y * 128;

  f32x4 acc[4][4];
  #pragma unroll
  for (int i = 0; i < 4; i++)
    #pragma unroll
    for (int j = 0; j < 4; j++) acc[i][j] = (f32x4){0.f, 0.f, 0.f, 0.f};

  const u16* Arow = A + (size_t)m0 * K;
  const u16* Brow = Bt + (size_t)n0 * K;
  const int lrow = t >> 3, lcol = (t & 7) * 8;

  for (int k0 = 0; k0 < K; k0 += 64) {
    __syncthreads();
    #pragma unroll
    for (int c = 0; c < 4; ++c) {
      gload_lds16(Arow + (size_t)(c * 32 + lrow) * K + k0 + lcol, As + c * 2048 + wid * 512);
      gload_lds16(Brow + (size_t)(c * 32 + lrow) * K + k0 + lcol, Bs + c * 2048 + wid * 512);
    }
    __syncthreads();
    #pragma unroll
    for (int kk = 0; kk < 64; kk += 32) {
      FragAB a[4], b[4];
      #pragma unroll
      for (int mi = 0; mi < 4; mi++)
        a[mi].u4 = *(const uint4*)&As[(wm * 64 + mi * 16 + r) * 64 + kk + g * 8];
      #pragma unroll
      for (int ni = 0; ni < 4; ni++)
        b[ni].u4 = *(const uint4*)&Bs[(wn * 64 + ni * 16 + r) * 64 + kk + g * 8];
      #pragma unroll
      for (int mi = 0; mi < 4; mi++)
        #pragma unroll
        for (int ni = 0; ni < 4; ni++)
          acc[mi][ni] = __builtin_amdgcn_mfma_f32_16x16x32_bf16(a[mi].v, b[ni].v, acc[mi][ni], 0, 0, 0);
    }
  }
  if (CT1 && (int)blockIdx.x >= nsplit) {
    u16* Ct = (u16*)Cp;
    #pragma unroll
    for (int mi = 0; mi < 4; mi++) {
      int row = m0 + wm * 64 + mi * 16 + g * 4;
      #pragma unroll
      for (int ni = 0; ni < 4; ni++) {
        int col = n0 + wn * 64 + ni * 16 + r;
        ushort4 hv;
        hv.x = f2bf(acc[mi][ni][0] * scale); hv.y = f2bf(acc[mi][ni][1] * scale);
        hv.z = f2bf(acc[mi][ni][2] * scale); hv.w = f2bf(acc[mi][ni][3] * scale);
        *(ushort4*)&Ct[(size_t)col * NROW + row] = hv;
      }
    }
  } else {
    #pragma unroll
    for (int mi = 0; mi < 4; mi++) {
      int row = m0 + wm * 64 + mi * 16 + g * 4;
      #pragma unroll
      for (int ni = 0; ni < 4; ni++) {
        int col = n0 + wn * 64 + ni * 16 + r;
        #pragma unroll
        for (int rr = 0; rr < 4; rr++) {
          if (CBF) ((u16*)Cp)[(size_t)(row + rr) * N + col] = f2bf(acc[mi][ni][rr] * scale);
          else     ((float*)Cp)[(size_t)(row + rr) * N + col] = acc[mi][ni][rr];
        }
      }
    }
  }
}

// ---------- MFMA flash attention, LDS-free ----------
// QBLK=128 (4 waves x 32 q-rows, Q in regs). K/V^T fragments loaded DIRECTLY
// global->registers (K/V is L2-resident; LDS staging was pure overhead).
// No barriers: waves independent, each stops at its own causal bound.
// K reg-double-buffered (explicit ping-pong, 2-unrolled loop); V issued before
// softmax so L2 latency hides under it. Swapped-operand QK^T/PV, in-lane
// softmax, defer-max, cvt_pk P-packing, setprio around MFMA.
__device__ __forceinline__ void attn_block(const u16* __restrict__ Q, const u16* __restrict__ K,
    const u16* __restrict__ VT, u16* __restrict__ O, int qb, int h, int b)
{
  const int t = threadIdx.x, lane = t & 63, w = t >> 6;
  const int r = lane & 15, g = lane >> 4;
  const int kvh = h >> 2;
  const int base = qb * 128 + w * 32;   // wave's first q-row

  FragAB qf[2][2];
  {
    const u16* Qg = Q + ((size_t)(b * 2048 + base)) * 2048 + h * 64;
    #pragma unroll
    for (int mb = 0; mb < 2; mb++)
      #pragma unroll
      for (int ks = 0; ks < 2; ks++)
        qf[mb][ks].u4 = *(const uint4*)(Qg + (size_t)(mb * 16 + r) * 2048 + ks * 32 + g * 8);
  }

  float m_run[2] = {-1e30f, -1e30f}, l_run[2] = {0.f, 0.f};
  f32x4 o[2][4];
  #pragma unroll
  for (int mb = 0; mb < 2; mb++)
    #pragma unroll
    for (int nd = 0; nd < 4; nd++) o[mb][nd] = (f32x4){0.f, 0.f, 0.f, 0.f};

  const u16* Kg0 = K + (size_t)(b * 2048) * 512 + kvh * 64;            // [key][512]
  const u16* Vg0 = VT + (size_t)(kvh * 64) * NROW + (size_t)b * 2048;  // [dim][4096]
  const int ntw = 2 * qb + (w >> 1) + 1;   // wave's causal tile count

  FragAB kfA[2][4], kfB[2][4], vf[2][4];

  auto loadK = [&](int jt, FragAB (&kf)[2][4]) {
    const u16* Kg = Kg0 + (size_t)jt * (64 * 512);
    #pragma unroll
    for (int ks = 0; ks < 2; ks++)
      #pragma unroll
      for (int kb = 0; kb < 4; kb++)
        kf[ks][kb].u4 = *(const uint4*)(Kg + (size_t)(kb * 16 + r) * 512 + ks * 32 + g * 8);
  };
  auto loadV = [&](int jt) {
    const u16* Vg = Vg0 + jt * 64;
    #pragma unroll
    for (int ks = 0; ks < 2; ks++)
      #pragma unroll
      for (int nd = 0; nd < 4; nd++) {
        const u16* bb = Vg + (size_t)(nd * 16 + r) * NROW + ks * 32 + g * 4;
        vf[ks][nd].q[0] = *(const uint2*)(bb);
        vf[ks][nd].q[1] = *(const uint2*)(bb + 16);
      }
  };

  auto tile = [&](FragAB (&kf)[2][4], int jt) {
    // QK^T swapped: st[mb][kb][i] = S[qrow = mb*16+r][key = jt*64 + kb*16 + g*4 + i]
    f32x4 st[2][4];
    #pragma unroll
    for (int mb = 0; mb < 2; mb++)
      #pragma unroll
      for (int kb = 0; kb < 4; kb++) st[mb][kb] = (f32x4){0.f, 0.f, 0.f, 0.f};
    #pragma unroll
    for (int ks = 0; ks < 2; ks++) {
      __builtin_amdgcn_s_setprio(1);
      #pragma unroll
      for (int mb = 0; mb < 2; mb++)
        #pragma unroll
        for (int kb = 0; kb < 4; kb++)
          st[mb][kb] = __builtin_amdgcn_mfma_f32_16x16x32_bf16(kf[ks][kb].v, qf[mb][ks].v, st[mb][kb], 0, 0, 0);
      __builtin_amdgcn_s_setprio(0);
    }

    FragAB pa[2][2];
    #pragma unroll
    for (int mb = 0; mb < 2; mb++) {
      const int rowg = base + mb * 16 + r;
      float sl[4][4];
      #pragma unroll
      for (int kb = 0; kb < 4; kb++)
        #pragma unroll
        for (int i = 0; i < 4; i++) sl[kb][i] = st[mb][kb][i];
      if (jt * 64 + 63 > base + mb * 16) {   // diagonal-crossing tile(s)
        const int kdel = jt * 64 + g * 4 - rowg;
        #pragma unroll
        for (int kb = 0; kb < 4; kb++)
          #pragma unroll
          for (int i = 0; i < 4; i++)
            if (kdel + kb * 16 + i > 0) sl[kb][i] = -1e30f;
      }
      float pm = sl[0][0];
      #pragma unroll
      for (int kb = 0; kb < 4; kb++)
        #pragma unroll
        for (int i = 0; i < 4; i++) pm = fmaxf(pm, sl[kb][i]);
      pm = fmaxf(pm, __shfl_xor(pm, 16));
      pm = fmaxf(pm, __shfl_xor(pm, 32));
      if (__any(pm > m_run[mb] + 8.f)) {   // defer-max rescale
        float mn = fmaxf(m_run[mb], pm);
        float corr = __builtin_exp2f(m_run[mb] - mn);
        m_run[mb] = mn;
        l_run[mb] *= corr;
        #pragma unroll
        for (int nd = 0; nd < 4; nd++)
          #pragma unroll
          for (int i = 0; i < 4; i++) o[mb][nd][i] *= corr;
      }
      float p[4][4]; float ls = 0.f;
      #pragma unroll
      for (int kb = 0; kb < 4; kb++)
        #pragma unroll
        for (int i = 0; i < 4; i++) { p[kb][i] = __builtin_exp2f(sl[kb][i] - m_run[mb]); ls += p[kb][i]; }
      ls += __shfl_xor(ls, 16);
      ls += __shfl_xor(ls, 32);
      l_run[mb] += ls;
      #pragma unroll
      for (int ks = 0; ks < 2; ks++) {
        pa[mb][ks].q[0] = make_uint2(cvtpk_bf16(p[2 * ks][0], p[2 * ks][1]),
                                     cvtpk_bf16(p[2 * ks][2], p[2 * ks][3]));
        pa[mb][ks].q[1] = make_uint2(cvtpk_bf16(p[2 * ks + 1][0], p[2 * ks + 1][1]),
                                     cvtpk_bf16(p[2 * ks + 1][2], p[2 * ks + 1][3]));
      }
    }

    // PV swapped: o^T += V^T @ P^T
    #pragma unroll
    for (int ks = 0; ks < 2; ks++) {
      __builtin_amdgcn_s_setprio(1);
      #pragma unroll
      for (int mb = 0; mb < 2; mb++)
        #pragma unroll
        for (int nd = 0; nd < 4; nd++)
          o[mb][nd] = __builtin_amdgcn_mfma_f32_16x16x32_bf16(vf[ks][nd].v, pa[mb][ks].v, o[mb][nd], 0, 0, 0);
      __builtin_amdgcn_s_setprio(0);
    }
  };

  loadK(0, kfA);
  int jt = 0;
  while (jt < ntw) {
    if (jt + 1 < ntw) loadK(jt + 1, kfB);   // prefetch next K into B set
    loadV(jt);                               // V latency hides under softmax
    tile(kfA, jt);
    ++jt;
    if (jt >= ntw) break;
    if (jt + 1 < ntw) loadK(jt + 1, kfA);
    loadV(jt);
    tile(kfB, jt);
    ++jt;
  }

  u16* Og = O + ((size_t)(b * 2048 + base)) * 2048 + h * 64;
  #pragma unroll
  for (int mb = 0; mb < 2; mb++) {
    float inv = 1.f / l_run[mb];
    #pragma unroll
    for (int nd = 0; nd < 4; nd++) {
      ushort4 hv;
      hv.x = f2bf(o[mb][nd][0] * inv); hv.y = f2bf(o[mb][nd][1] * inv);
      hv.z = f2bf(o[mb][nd][2] * inv); hv.w = f2bf(o[mb][nd][3] * inv);
      *(ushort4*)(Og + (size_t)(mb * 16 + r) * 2048 + nd * 16 + g * 4) = hv;
    }
  }
}

// Paired q-blocks (bx, 15-bx): constant work per block; no LDS, no barriers.
__global__ __launch_bounds__(256, 2)
void attn_mfma(const u16* __restrict__ Q, const u16* __restrict__ K,
               const u16* __restrict__ VT, u16* __restrict__ O)
{
  const int h = blockIdx.y, b = blockIdx.z;
  attn_block(Q, K, VT, O, 15 - (int)blockIdx.x, h, b);
  attn_block(Q, K, VT, O, (int)blockIdx.x, h, b);
}

extern "C" void kernel_launch(void* const* d_in, const int* in_sizes, int n_in,
                              void* d_out, int out_size, void* d_ws, size_t ws_size,
                              hipStream_t stream)
{
  (void)in_sizes; (void)n_in; (void)out_size; (void)ws_size;
  const float* X  = (const float*)d_in[0];
  const float* Wq = (const float*)d_in[1];
  const float* Wk = (const float*)d_in[2];
  const float* Wv = (const float*)d_in[3];
  const float* Wo = (const float*)d_in[4];
  float* out = (float*)d_out;

  u16* Xb  = (u16*)d_ws;                         // [4096][2048]
  u16* Qb  = Xb  + (size_t)NROW * HID;           // [4096][2048] (pre-scaled by SC2)
  u16* Kb  = Qb  + (size_t)NROW * HID;           // [4096][512]
  u16* VTb = Kb  + (size_t)NROW * KVH;           // [512][4096]  (V transposed)
  u16* Wqt = VTb + (size_t)NROW * KVH;           // [2048][2048]
  u16* Wkt = Wqt + (size_t)HID * HID;            // [512][2048]
  u16* Wvt = Wkt + (size_t)HID * KVH;
  u16* AOb = Xb;    // alias: X dead after KV gemm
  u16* Wot = Wqt;   // alias: Wqt dead after Q gemm

  conv_bf16<<<2048, 256, 0, stream>>>(X, Xb, NROW * HID / 4);
  transpose_conv<<<dim3(64, 64), dim3(32, 8), 0, stream>>>(Wq, Wqt, HID, HID);
  transpose_conv2<<<dim3(16, 64, 2), dim3(32, 8), 0, stream>>>(Wk, Wv, Wkt, Wvt, HID, KVH);
  gemm_bt<1, 0><<<dim3(16, 32), 256, 0, stream>>>(Xb, Wqt, Wqt, Qb, Qb, 16, HID, HID, SC2);
  gemm_bt<1, 1><<<dim3(8, 32), 256, 0, stream>>>(Xb, Wkt, Wvt, Kb, VTb, 4, KVH, HID, 1.f);
  transpose_conv<<<dim3(64, 64), dim3(32, 8), 0, stream>>>(Wo, Wot, HID, HID);
  attn_mfma<<<dim3(8, 32, 2), 256, 0, stream>>>(Qb, Kb, VTb, AOb);
  gemm_bt<0, 0><<<dim3(16, 32), 256, 0, stream>>>(AOb, Wot, Wot, out, out, 16, HID, HID, 1.f);
}

// Round 8
// 346.846 us; speedup vs baseline: 1.0035x; 1.0035x over previous
//
#include <hip/hip_runtime.h>

typedef unsigned short u16;
typedef unsigned int u32;
typedef __attribute__((ext_vector_type(8))) short short8_t;
typedef __attribute__((ext_vector_type(4))) float f32x4;

#define HID 2048
#define KVH 512
#define NROW 4096   // B*S
#define SC2 0.18033688011112042f   // (1/sqrt(64)) * log2(e)

__device__ __forceinline__ u16 f2bf(float f){
  u32 u = __builtin_bit_cast(u32, f);
  u += 0x7fffu + ((u >> 16) & 1u);   // round-to-nearest-even
  return (u16)(u >> 16);
}
__device__ __forceinline__ u32 cvtpk_bf16(float lo, float hi){
  u32 r; asm("v_cvt_pk_bf16_f32 %0, %1, %2" : "=v"(r) : "v"(lo), "v"(hi)); return r;
}

union FragAB { short8_t v; uint4 u4; uint2 q[2]; };

__device__ __forceinline__ void gload_lds16(const u16* g, u16* l){
  __builtin_amdgcn_global_load_lds((const __attribute__((address_space(1))) void*)g,
                                   (__attribute__((address_space(3))) void*)l, 16, 0, 0);
}

// ---------- prep: fp32 -> bf16 convert ----------
__global__ __launch_bounds__(256)
void conv_bf16(const float* __restrict__ X, u16* __restrict__ Y, int n4)
{
  for (int i = blockIdx.x * 256 + threadIdx.x; i < n4; i += gridDim.x * 256) {
    float4 v = ((const float4*)X)[i];
    ushort4 h; h.x = f2bf(v.x); h.y = f2bf(v.y); h.z = f2bf(v.z); h.w = f2bf(v.w);
    ((ushort4*)Y)[i] = h;
  }
}

// ---------- prep: W[K][N] fp32 -> Wt[N][K] bf16 ----------
__global__ __launch_bounds__(256)
void transpose_conv(const float* __restrict__ W, u16* __restrict__ Wt, int K, int N)
{
  __shared__ float tile[32][33];
  int x = blockIdx.x * 32 + threadIdx.x;
  int y0 = blockIdx.y * 32;
  #pragma unroll
  for (int j = threadIdx.y; j < 32; j += 8)
    tile[j][threadIdx.x] = W[(size_t)(y0 + j) * N + x];
  __syncthreads();
  #pragma unroll
  for (int j = threadIdx.y; j < 32; j += 8)
    Wt[(size_t)(blockIdx.x * 32 + j) * K + y0 + threadIdx.x] = f2bf(tile[threadIdx.x][j]);
}

// two same-shape transposes in one launch (z selects)
__global__ __launch_bounds__(256)
void transpose_conv2(const float* __restrict__ W0, const float* __restrict__ W1,
                     u16* __restrict__ T0, u16* __restrict__ T1, int K, int N)
{
  __shared__ float tile[32][33];
  const float* W = blockIdx.z ? W1 : W0;
  u16* Wt = blockIdx.z ? T1 : T0;
  int x = blockIdx.x * 32 + threadIdx.x;
  int y0 = blockIdx.y * 32;
  #pragma unroll
  for (int j = threadIdx.y; j < 32; j += 8)
    tile[j][threadIdx.x] = W[(size_t)(y0 + j) * N + x];
  __syncthreads();
  #pragma unroll
  for (int j = threadIdx.y; j < 32; j += 8)
    Wt[(size_t)(blockIdx.x * 32 + j) * K + y0 + threadIdx.x] = f2bf(tile[threadIdx.x][j]);
}

// ---------- bf16 GEMM, B^T input (m97 structure) ----------
template<int CBF, int CT1>
__global__ __launch_bounds__(256)
void gemm_bt(const u16* __restrict__ A, const u16* __restrict__ B0,
             const u16* __restrict__ B1, void* __restrict__ C0,
             void* __restrict__ C1, int nsplit, int N, int K, float scale)
{
  __shared__ __align__(16) u16 As[128 * 64];
  __shared__ __align__(16) u16 Bs[128 * 64];
  const int t = threadIdx.x, lane = t & 63, wid = t >> 6;
  const int wm = wid >> 1, wn = wid & 1;
  const int r = lane & 15, g = lane >> 4;
  const u16* Bt; char* Cp; int n0;
  if ((int)blockIdx.x < nsplit) { Bt = B0; Cp = (char*)C0; n0 = blockIdx.x * 128; }
  else { Bt = B1; Cp = (char*)C1; n0 = ((int)blockIdx.x - nsplit) * 128; }
  const int m0 = blockIdx.y * 128;

  f32x4 acc[4][4];
  #pragma unroll
  for (int i = 0; i < 4; i++)
    #pragma unroll
    for (int j = 0; j < 4; j++) acc[i][j] = (f32x4){0.f, 0.f, 0.f, 0.f};

  const u16* Arow = A + (size_t)m0 * K;
  const u16* Brow = Bt + (size_t)n0 * K;
  const int lrow = t >> 3, lcol = (t & 7) * 8;

  for (int k0 = 0; k0 < K; k0 += 64) {
    __syncthreads();
    #pragma unroll
    for (int c = 0; c < 4; ++c) {
      gload_lds16(Arow + (size_t)(c * 32 + lrow) * K + k0 + lcol, As + c * 2048 + wid * 512);
      gload_lds16(Brow + (size_t)(c * 32 + lrow) * K + k0 + lcol, Bs + c * 2048 + wid * 512);
    }
    __syncthreads();
    #pragma unroll
    for (int kk = 0; kk < 64; kk += 32) {
      FragAB a[4], b[4];
      #pragma unroll
      for (int mi = 0; mi < 4; mi++)
        a[mi].u4 = *(const uint4*)&As[(wm * 64 + mi * 16 + r) * 64 + kk + g * 8];
      #pragma unroll
      for (int ni = 0; ni < 4; ni++)
        b[ni].u4 = *(const uint4*)&Bs[(wn * 64 + ni * 16 + r) * 64 + kk + g * 8];
      #pragma unroll
      for (int mi = 0; mi < 4; mi++)
        #pragma unroll
        for (int ni = 0; ni < 4; ni++)
          acc[mi][ni] = __builtin_amdgcn_mfma_f32_16x16x32_bf16(a[mi].v, b[ni].v, acc[mi][ni], 0, 0, 0);
    }
  }
  if (CT1 && (int)blockIdx.x >= nsplit) {
    u16* Ct = (u16*)Cp;
    #pragma unroll
    for (int mi = 0; mi < 4; mi++) {
      int row = m0 + wm * 64 + mi * 16 + g * 4;
      #pragma unroll
      for (int ni = 0; ni < 4; ni++) {
        int col = n0 + wn * 64 + ni * 16 + r;
        ushort4 hv;
        hv.x = f2bf(acc[mi][ni][0] * scale); hv.y = f2bf(acc[mi][ni][1] * scale);
        hv.z = f2bf(acc[mi][ni][2] * scale); hv.w = f2bf(acc[mi][ni][3] * scale);
        *(ushort4*)&Ct[(size_t)col * NROW + row] = hv;
      }
    }
  } else {
    #pragma unroll
    for (int mi = 0; mi < 4; mi++) {
      int row = m0 + wm * 64 + mi * 16 + g * 4;
      #pragma unroll
      for (int ni = 0; ni < 4; ni++) {
        int col = n0 + wn * 64 + ni * 16 + r;
        #pragma unroll
        for (int rr = 0; rr < 4; rr++) {
          if (CBF) ((u16*)Cp)[(size_t)(row + rr) * N + col] = f2bf(acc[mi][ni][rr] * scale);
          else     ((float*)Cp)[(size_t)(row + rr) * N + col] = acc[mi][ni][rr];
        }
      }
    }
  }
}

// ---------- MFMA flash attention (R5 structure, unpaired grid) ----------
// QBLK=128 (4 waves x 32 q-rows, Q in regs). Swapped-operand QK^T/PV, in-lane
// softmax, defer-max, cvt_pk P-packing, async-staged double-buffered K/V LDS
// (one barrier per tile). One qb per block, longest-first; 1024 blocks = 4/CU.
__global__ __launch_bounds__(256, 4)
void attn_mfma(const u16* __restrict__ Q, const u16* __restrict__ K,
               const u16* __restrict__ VT, u16* __restrict__ O)
{
  __shared__ __align__(16) u16 Ks0[64 * 72];
  __shared__ __align__(16) u16 Vt0[64 * 72];
  __shared__ __align__(16) u16 Ks1[64 * 72];
  __shared__ __align__(16) u16 Vt1[64 * 72];
  const int qb = 15 - (int)blockIdx.x;   // longest blocks dispatch first
  const int h = blockIdx.y, b = blockIdx.z;
  const int t = threadIdx.x, lane = t & 63, w = t >> 6;
  const int r = lane & 15, g = lane >> 4;
  const int kvh = h >> 2;
  const int base = qb * 128 + w * 32;

  FragAB qf[2][2];
  {
    const u16* Qg = Q + ((size_t)(b * 2048 + base)) * 2048 + h * 64;
    #pragma unroll
    for (int mb = 0; mb < 2; mb++)
      #pragma unroll
      for (int ks = 0; ks < 2; ks++)
        qf[mb][ks].u4 = *(const uint4*)(Qg + (size_t)(mb * 16 + r) * 2048 + ks * 32 + g * 8);
  }

  float m_run[2] = {-1e30f, -1e30f}, l_run[2] = {0.f, 0.f};
  f32x4 o[2][4];
  #pragma unroll
  for (int mb = 0; mb < 2; mb++)
    #pragma unroll
    for (int nd = 0; nd < 4; nd++) o[mb][nd] = (f32x4){0.f, 0.f, 0.f, 0.f};

  const u16* Kg0 = K + (size_t)(b * 2048) * 512 + kvh * 64;
  const u16* Vg0 = VT + (size_t)(kvh * 64) * NROW + (size_t)b * 2048;
  const int nt = 2 * qb + 2;
  const int srow = t >> 3, scol = (t & 7) * 8;

  uint4 kr0, kr1, vr0, vr1;   // staging regs (issue-early / write-late)
  auto loadt = [&](int jt) {
    const u16* Kg = Kg0 + (size_t)(jt * 64) * 512;
    kr0 = *(const uint4*)(Kg + (size_t)srow * 512 + scol);
    kr1 = *(const uint4*)(Kg + (size_t)(srow + 32) * 512 + scol);
    const u16* Vg = Vg0 + jt * 64;
    vr0 = *(const uint4*)(Vg + (size_t)srow * NROW + scol);
    vr1 = *(const uint4*)(Vg + (size_t)(srow + 32) * NROW + scol);
  };
  auto writet = [&](u16* Ks, u16* Vt) {
    *(uint4*)&Ks[srow * 72 + scol] = kr0;
    *(uint4*)&Ks[(srow + 32) * 72 + scol] = kr1;
    *(uint4*)&Vt[srow * 72 + scol] = vr0;
    *(uint4*)&Vt[(srow + 32) * 72 + scol] = vr1;
  };

  loadt(0);
  writet(Ks0, Vt0);
  __syncthreads();

  for (int jt = 0; jt < nt; ++jt) {
    u16* Ks = (jt & 1) ? Ks1 : Ks0;
    u16* Vt = (jt & 1) ? Vt1 : Vt0;
    if (jt + 1 < nt) loadt(jt + 1);

    if (jt * 64 <= base + 31) {  // wave participates
      f32x4 st[2][4];
      #pragma unroll
      for (int mb = 0; mb < 2; mb++)
        #pragma unroll
        for (int kb = 0; kb < 4; kb++) st[mb][kb] = (f32x4){0.f, 0.f, 0.f, 0.f};
      #pragma unroll
      for (int ks = 0; ks < 2; ks++) {
        FragAB kf[4];
        #pragma unroll
        for (int kb = 0; kb < 4; kb++)
          kf[kb].u4 = *(const uint4*)&Ks[(kb * 16 + r) * 72 + ks * 32 + g * 8];
        __builtin_amdgcn_s_setprio(1);
        #pragma unroll
        for (int mb = 0; mb < 2; mb++)
          #pragma unroll
          for (int kb = 0; kb < 4; kb++)
            st[mb][kb] = __builtin_amdgcn_mfma_f32_16x16x32_bf16(kf[kb].v, qf[mb][ks].v, st[mb][kb], 0, 0, 0);
        __builtin_amdgcn_s_setprio(0);
      }

      FragAB pa[2][2];
      #pragma unroll
      for (int mb = 0; mb < 2; mb++) {
        const int rowg = base + mb * 16 + r;
        float sl[4][4];
        #pragma unroll
        for (int kb = 0; kb < 4; kb++)
          #pragma unroll
          for (int i = 0; i < 4; i++) sl[kb][i] = st[mb][kb][i];
        if (jt * 64 + 63 > base + mb * 16) {   // tile crosses diagonal
          const int kdel = jt * 64 + g * 4 - rowg;
          #pragma unroll
          for (int kb = 0; kb < 4; kb++)
            #pragma unroll
            for (int i = 0; i < 4; i++)
              if (kdel + kb * 16 + i > 0) sl[kb][i] = -1e30f;
        }
        float pm = sl[0][0];
        #pragma unroll
        for (int kb = 0; kb < 4; kb++)
          #pragma unroll
          for (int i = 0; i < 4; i++) pm = fmaxf(pm, sl[kb][i]);
        pm = fmaxf(pm, __shfl_xor(pm, 16));
        pm = fmaxf(pm, __shfl_xor(pm, 32));
        if (__any(pm > m_run[mb] + 8.f)) {   // defer-max rescale
          float mn = fmaxf(m_run[mb], pm);
          float corr = __builtin_exp2f(m_run[mb] - mn);
          m_run[mb] = mn;
          l_run[mb] *= corr;
          #pragma unroll
          for (int nd = 0; nd < 4; nd++)
            #pragma unroll
            for (int i = 0; i < 4; i++) o[mb][nd][i] *= corr;
        }
        float p[4][4]; float ls = 0.f;
        #pragma unroll
        for (int kb = 0; kb < 4; kb++)
          #pragma unroll
          for (int i = 0; i < 4; i++) { p[kb][i] = __builtin_exp2f(sl[kb][i] - m_run[mb]); ls += p[kb][i]; }
        ls += __shfl_xor(ls, 16);
        ls += __shfl_xor(ls, 32);
        l_run[mb] += ls;
        #pragma unroll
        for (int ks = 0; ks < 2; ks++) {
          pa[mb][ks].q[0] = make_uint2(cvtpk_bf16(p[2 * ks][0], p[2 * ks][1]),
                                       cvtpk_bf16(p[2 * ks][2], p[2 * ks][3]));
          pa[mb][ks].q[1] = make_uint2(cvtpk_bf16(p[2 * ks + 1][0], p[2 * ks + 1][1]),
                                       cvtpk_bf16(p[2 * ks + 1][2], p[2 * ks + 1][3]));
        }
      }

      #pragma unroll
      for (int ks = 0; ks < 2; ks++) {
        FragAB vf[4];
        #pragma unroll
        for (int nd = 0; nd < 4; nd++) {
          const u16* bb = &Vt[(nd * 16 + r) * 72 + ks * 32 + g * 4];
          vf[nd].q[0] = *(const uint2*)(bb);
          vf[nd].q[1] = *(const uint2*)(bb + 16);
        }
        __builtin_amdgcn_s_setprio(1);
        #pragma unroll
        for (int mb = 0; mb < 2; mb++)
          #pragma unroll
          for (int nd = 0; nd < 4; nd++)
            o[mb][nd] = __builtin_amdgcn_mfma_f32_16x16x32_bf16(vf[nd].v, pa[mb][ks].v, o[mb][nd], 0, 0, 0);
        __builtin_amdgcn_s_setprio(0);
      }
    }

    if (jt + 1 < nt) writet((jt & 1) ? Ks0 : Ks1, (jt & 1) ? Vt0 : Vt1);
    __syncthreads();   // one barrier per tile
  }

  u16* Og = O + ((size_t)(b * 2048 + base)) * 2048 + h * 64;
  #pragma unroll
  for (int mb = 0; mb < 2; mb++) {
    float inv = 1.f / l_run[mb];
    #pragma unroll
    for (int nd = 0; nd < 4; nd++) {
      ushort4 hv;
      hv.x = f2bf(o[mb][nd][0] * inv); hv.y = f2bf(o[mb][nd][1] * inv);
      hv.z = f2bf(o[mb][nd][2] * inv); hv.w = f2bf(o[mb][nd][3] * inv);
      *(ushort4*)(Og + (size_t)(mb * 16 + r) * 2048 + nd * 16 + g * 4) = hv;
    }
  }
}

extern "C" void kernel_launch(void* const* d_in, const int* in_sizes, int n_in,
                              void* d_out, int out_size, void* d_ws, size_t ws_size,
                              hipStream_t stream)
{
  (void)in_sizes; (void)n_in; (void)out_size; (void)ws_size;
  const float* X  = (const float*)d_in[0];
  const float* Wq = (const float*)d_in[1];
  const float* Wk = (const float*)d_in[2];
  const float* Wv = (const float*)d_in[3];
  const float* Wo = (const float*)d_in[4];
  float* out = (float*)d_out;

  u16* Xb  = (u16*)d_ws;                         // [4096][2048]
  u16* Qb  = Xb  + (size_t)NROW * HID;           // [4096][2048] (pre-scaled by SC2)
  u16* Kb  = Qb  + (size_t)NROW * HID;           // [4096][512]
  u16* VTb = Kb  + (size_t)NROW * KVH;           // [512][4096]  (V transposed)
  u16* Wqt = VTb + (size_t)NROW * KVH;           // [2048][2048]
  u16* Wkt = Wqt + (size_t)HID * HID;            // [512][2048]
  u16* Wvt = Wkt + (size_t)HID * KVH;
  u16* AOb = Xb;    // alias: X dead after KV gemm
  u16* Wot = Wqt;   // alias: Wqt dead after Q gemm

  conv_bf16<<<2048, 256, 0, stream>>>(X, Xb, NROW * HID / 4);
  transpose_conv<<<dim3(64, 64), dim3(32, 8), 0, stream>>>(Wq, Wqt, HID, HID);
  transpose_conv2<<<dim3(16, 64, 2), dim3(32, 8), 0, stream>>>(Wk, Wv, Wkt, Wvt, HID, KVH);
  gemm_bt<1, 0><<<dim3(16, 32), 256, 0, stream>>>(Xb, Wqt, Wqt, Qb, Qb, 16, HID, HID, SC2);
  gemm_bt<1, 1><<<dim3(8, 32), 256, 0, stream>>>(Xb, Wkt, Wvt, Kb, VTb, 4, KVH, HID, 1.f);
  transpose_conv<<<dim3(64, 64), dim3(32, 8), 0, stream>>>(Wo, Wot, HID, HID);
  attn_mfma<<<dim3(16, 32, 2), 256, 0, stream>>>(Qb, Kb, VTb, AOb);
  gemm_bt<0, 0><<<dim3(16, 32), 256, 0, stream>>>(AOb, Wot, Wot, out, out, 16, HID, HID, 1.f);
}

// Round 9
// 322.335 us; speedup vs baseline: 1.0799x; 1.0760x over previous
//
#include <hip/hip_runtime.h>

typedef unsigned short u16;
typedef unsigned int u32;
typedef __attribute__((ext_vector_type(8))) short short8_t;
typedef __attribute__((ext_vector_type(4))) float f32x4;

#define HID 2048
#define KVH 512
#define NROW 4096   // B*S
#define SC2 0.18033688011112042f   // (1/sqrt(64)) * log2(e)

__device__ __forceinline__ u16 f2bf(float f){
  u32 u = __builtin_bit_cast(u32, f);
  u += 0x7fffu + ((u >> 16) & 1u);   // round-to-nearest-even
  return (u16)(u >> 16);
}
__device__ __forceinline__ u32 cvtpk_bf16(float lo, float hi){
  u32 r; asm("v_cvt_pk_bf16_f32 %0, %1, %2" : "=v"(r) : "v"(lo), "v"(hi)); return r;
}

union FragAB { short8_t v; uint4 u4; uint2 q[2]; };

__device__ __forceinline__ void gload_lds16(const u16* g, u16* l){
  __builtin_amdgcn_global_load_lds((const __attribute__((address_space(1))) void*)g,
                                   (__attribute__((address_space(3))) void*)l, 16, 0, 0);
}

// ---------- prep: fp32 -> bf16 convert ----------
__global__ __launch_bounds__(256)
void conv_bf16(const float* __restrict__ X, u16* __restrict__ Y, int n4)
{
  for (int i = blockIdx.x * 256 + threadIdx.x; i < n4; i += gridDim.x * 256) {
    float4 v = ((const float4*)X)[i];
    ushort4 h; h.x = f2bf(v.x); h.y = f2bf(v.y); h.z = f2bf(v.z); h.w = f2bf(v.w);
    ((ushort4*)Y)[i] = h;
  }
}

// ---------- prep: W[K][N] fp32 -> Wt[N][K] bf16 ----------
__global__ __launch_bounds__(256)
void transpose_conv(const float* __restrict__ W, u16* __restrict__ Wt, int K, int N)
{
  __shared__ float tile[32][33];
  int x = blockIdx.x * 32 + threadIdx.x;
  int y0 = blockIdx.y * 32;
  #pragma unroll
  for (int j = threadIdx.y; j < 32; j += 8)
    tile[j][threadIdx.x] = W[(size_t)(y0 + j) * N + x];
  __syncthreads();
  #pragma unroll
  for (int j = threadIdx.y; j < 32; j += 8)
    Wt[(size_t)(blockIdx.x * 32 + j) * K + y0 + threadIdx.x] = f2bf(tile[threadIdx.x][j]);
}

// two same-shape transposes in one launch (z selects)
__global__ __launch_bounds__(256)
void transpose_conv2(const float* __restrict__ W0, const float* __restrict__ W1,
                     u16* __restrict__ T0, u16* __restrict__ T1, int K, int N)
{
  __shared__ float tile[32][33];
  const float* W = blockIdx.z ? W1 : W0;
  u16* Wt = blockIdx.z ? T1 : T0;
  int x = blockIdx.x * 32 + threadIdx.x;
  int y0 = blockIdx.y * 32;
  #pragma unroll
  for (int j = threadIdx.y; j < 32; j += 8)
    tile[j][threadIdx.x] = W[(size_t)(y0 + j) * N + x];
  __syncthreads();
  #pragma unroll
  for (int j = threadIdx.y; j < 32; j += 8)
    Wt[(size_t)(blockIdx.x * 32 + j) * K + y0 + threadIdx.x] = f2bf(tile[threadIdx.x][j]);
}

// ---------- bf16 GEMM, B^T input (m97 structure) ----------
template<int CBF, int CT1>
__global__ __launch_bounds__(256)
void gemm_bt(const u16* __restrict__ A, const u16* __restrict__ B0,
             const u16* __restrict__ B1, void* __restrict__ C0,
             void* __restrict__ C1, int nsplit, int N, int K, float scale)
{
  __shared__ __align__(16) u16 As[128 * 64];
  __shared__ __align__(16) u16 Bs[128 * 64];
  const int t = threadIdx.x, lane = t & 63, wid = t >> 6;
  const int wm = wid >> 1, wn = wid & 1;
  const int r = lane & 15, g = lane >> 4;
  const u16* Bt; char* Cp; int n0;
  if ((int)blockIdx.x < nsplit) { Bt = B0; Cp = (char*)C0; n0 = blockIdx.x * 128; }
  else { Bt = B1; Cp = (char*)C1; n0 = ((int)blockIdx.x - nsplit) * 128; }
  const int m0 = blockIdx.y * 128;

  f32x4 acc[4][4];
  #pragma unroll
  for (int i = 0; i < 4; i++)
    #pragma unroll
    for (int j = 0; j < 4; j++) acc[i][j] = (f32x4){0.f, 0.f, 0.f, 0.f};

  const u16* Arow = A + (size_t)m0 * K;
  const u16* Brow = Bt + (size_t)n0 * K;
  const int lrow = t >> 3, lcol = (t & 7) * 8;

  for (int k0 = 0; k0 < K; k0 += 64) {
    __syncthreads();
    #pragma unroll
    for (int c = 0; c < 4; ++c) {
      gload_lds16(Arow + (size_t)(c * 32 + lrow) * K + k0 + lcol, As + c * 2048 + wid * 512);
      gload_lds16(Brow + (size_t)(c * 32 + lrow) * K + k0 + lcol, Bs + c * 2048 + wid * 512);
    }
    __syncthreads();
    #pragma unroll
    for (int kk = 0; kk < 64; kk += 32) {
      FragAB a[4], b[4];
      #pragma unroll
      for (int mi = 0; mi < 4; mi++)
        a[mi].u4 = *(const uint4*)&As[(wm * 64 + mi * 16 + r) * 64 + kk + g * 8];
      #pragma unroll
      for (int ni = 0; ni < 4; ni++)
        b[ni].u4 = *(const uint4*)&Bs[(wn * 64 + ni * 16 + r) * 64 + kk + g * 8];
      #pragma unroll
      for (int mi = 0; mi < 4; mi++)
        #pragma unroll
        for (int ni = 0; ni < 4; ni++)
          acc[mi][ni] = __builtin_amdgcn_mfma_f32_16x16x32_bf16(a[mi].v, b[ni].v, acc[mi][ni], 0, 0, 0);
    }
  }
  if (CT1 && (int)blockIdx.x >= nsplit) {
    u16* Ct = (u16*)Cp;
    #pragma unroll
    for (int mi = 0; mi < 4; mi++) {
      int row = m0 + wm * 64 + mi * 16 + g * 4;
      #pragma unroll
      for (int ni = 0; ni < 4; ni++) {
        int col = n0 + wn * 64 + ni * 16 + r;
        ushort4 hv;
        hv.x = f2bf(acc[mi][ni][0] * scale); hv.y = f2bf(acc[mi][ni][1] * scale);
        hv.z = f2bf(acc[mi][ni][2] * scale); hv.w = f2bf(acc[mi][ni][3] * scale);
        *(ushort4*)&Ct[(size_t)col * NROW + row] = hv;
      }
    }
  } else {
    #pragma unroll
    for (int mi = 0; mi < 4; mi++) {
      int row = m0 + wm * 64 + mi * 16 + g * 4;
      #pragma unroll
      for (int ni = 0; ni < 4; ni++) {
        int col = n0 + wn * 64 + ni * 16 + r;
        #pragma unroll
        for (int rr = 0; rr < 4; rr++) {
          if (CBF) ((u16*)Cp)[(size_t)(row + rr) * N + col] = f2bf(acc[mi][ni][rr] * scale);
          else     ((float*)Cp)[(size_t)(row + rr) * N + col] = acc[mi][ni][rr];
        }
      }
    }
  }
}

// ---------- MFMA flash attention (R5 structure, unpaired longest-first grid) ----------
// QBLK=128 (4 waves x 32 q-rows, Q in regs). Swapped-operand QK^T/PV, in-lane
// softmax, defer-max, cvt_pk P-packing, async-staged double-buffered K/V LDS
// (one barrier per tile). One qb per block, longest-first. NO min-waves clamp:
// natural limits (LDS 147.5/160 KB, VGPR 464/512 per SIMD) give 4 blocks/CU
// without forcing spills (R8 lesson: launch_bounds(256,4) -> VGPR 64 -> 237MB scratch).
__global__ __launch_bounds__(256)
void attn_mfma(const u16* __restrict__ Q, const u16* __restrict__ K,
               const u16* __restrict__ VT, u16* __restrict__ O)
{
  __shared__ __align__(16) u16 Ks0[64 * 72];
  __shared__ __align__(16) u16 Vt0[64 * 72];
  __shared__ __align__(16) u16 Ks1[64 * 72];
  __shared__ __align__(16) u16 Vt1[64 * 72];
  const int qb = 15 - (int)blockIdx.x;   // longest blocks dispatch first
  const int h = blockIdx.y, b = blockIdx.z;
  const int t = threadIdx.x, lane = t & 63, w = t >> 6;
  const int r = lane & 15, g = lane >> 4;
  const int kvh = h >> 2;
  const int base = qb * 128 + w * 32;

  FragAB qf[2][2];
  {
    const u16* Qg = Q + ((size_t)(b * 2048 + base)) * 2048 + h * 64;
    #pragma unroll
    for (int mb = 0; mb < 2; mb++)
      #pragma unroll
      for (int ks = 0; ks < 2; ks++)
        qf[mb][ks].u4 = *(const uint4*)(Qg + (size_t)(mb * 16 + r) * 2048 + ks * 32 + g * 8);
  }

  float m_run[2] = {-1e30f, -1e30f}, l_run[2] = {0.f, 0.f};
  f32x4 o[2][4];
  #pragma unroll
  for (int mb = 0; mb < 2; mb++)
    #pragma unroll
    for (int nd = 0; nd < 4; nd++) o[mb][nd] = (f32x4){0.f, 0.f, 0.f, 0.f};

  const u16* Kg0 = K + (size_t)(b * 2048) * 512 + kvh * 64;
  const u16* Vg0 = VT + (size_t)(kvh * 64) * NROW + (size_t)b * 2048;
  const int nt = 2 * qb + 2;
  const int srow = t >> 3, scol = (t & 7) * 8;

  uint4 kr0, kr1, vr0, vr1;   // staging regs (issue-early / write-late)
  auto loadt = [&](int jt) {
    const u16* Kg = Kg0 + (size_t)(jt * 64) * 512;
    kr0 = *(const uint4*)(Kg + (size_t)srow * 512 + scol);
    kr1 = *(const uint4*)(Kg + (size_t)(srow + 32) * 512 + scol);
    const u16* Vg = Vg0 + jt * 64;
    vr0 = *(const uint4*)(Vg + (size_t)srow * NROW + scol);
    vr1 = *(const uint4*)(Vg + (size_t)(srow + 32) * NROW + scol);
  };
  auto writet = [&](u16* Ks, u16* Vt) {
    *(uint4*)&Ks[srow * 72 + scol] = kr0;
    *(uint4*)&Ks[(srow + 32) * 72 + scol] = kr1;
    *(uint4*)&Vt[srow * 72 + scol] = vr0;
    *(uint4*)&Vt[(srow + 32) * 72 + scol] = vr1;
  };

  loadt(0);
  writet(Ks0, Vt0);
  __syncthreads();

  for (int jt = 0; jt < nt; ++jt) {
    u16* Ks = (jt & 1) ? Ks1 : Ks0;
    u16* Vt = (jt & 1) ? Vt1 : Vt0;
    if (jt + 1 < nt) loadt(jt + 1);

    if (jt * 64 <= base + 31) {  // wave participates
      f32x4 st[2][4];
      #pragma unroll
      for (int mb = 0; mb < 2; mb++)
        #pragma unroll
        for (int kb = 0; kb < 4; kb++) st[mb][kb] = (f32x4){0.f, 0.f, 0.f, 0.f};
      #pragma unroll
      for (int ks = 0; ks < 2; ks++) {
        FragAB kf[4];
        #pragma unroll
        for (int kb = 0; kb < 4; kb++)
          kf[kb].u4 = *(const uint4*)&Ks[(kb * 16 + r) * 72 + ks * 32 + g * 8];
        __builtin_amdgcn_s_setprio(1);
        #pragma unroll
        for (int mb = 0; mb < 2; mb++)
          #pragma unroll
          for (int kb = 0; kb < 4; kb++)
            st[mb][kb] = __builtin_amdgcn_mfma_f32_16x16x32_bf16(kf[kb].v, qf[mb][ks].v, st[mb][kb], 0, 0, 0);
        __builtin_amdgcn_s_setprio(0);
      }

      FragAB pa[2][2];
      #pragma unroll
      for (int mb = 0; mb < 2; mb++) {
        const int rowg = base + mb * 16 + r;
        float sl[4][4];
        #pragma unroll
        for (int kb = 0; kb < 4; kb++)
          #pragma unroll
          for (int i = 0; i < 4; i++) sl[kb][i] = st[mb][kb][i];
        if (jt * 64 + 63 > base + mb * 16) {   // tile crosses diagonal
          const int kdel = jt * 64 + g * 4 - rowg;
          #pragma unroll
          for (int kb = 0; kb < 4; kb++)
            #pragma unroll
            for (int i = 0; i < 4; i++)
              if (kdel + kb * 16 + i > 0) sl[kb][i] = -1e30f;
        }
        float pm = sl[0][0];
        #pragma unroll
        for (int kb = 0; kb < 4; kb++)
          #pragma unroll
          for (int i = 0; i < 4; i++) pm = fmaxf(pm, sl[kb][i]);
        pm = fmaxf(pm, __shfl_xor(pm, 16));
        pm = fmaxf(pm, __shfl_xor(pm, 32));
        if (__any(pm > m_run[mb] + 8.f)) {   // defer-max rescale
          float mn = fmaxf(m_run[mb], pm);
          float corr = __builtin_exp2f(m_run[mb] - mn);
          m_run[mb] = mn;
          l_run[mb] *= corr;
          #pragma unroll
          for (int nd = 0; nd < 4; nd++)
            #pragma unroll
            for (int i = 0; i < 4; i++) o[mb][nd][i] *= corr;
        }
        float p[4][4]; float ls = 0.f;
        #pragma unroll
        for (int kb = 0; kb < 4; kb++)
          #pragma unroll
          for (int i = 0; i < 4; i++) { p[kb][i] = __builtin_exp2f(sl[kb][i] - m_run[mb]); ls += p[kb][i]; }
        ls += __shfl_xor(ls, 16);
        ls += __shfl_xor(ls, 32);
        l_run[mb] += ls;
        #pragma unroll
        for (int ks = 0; ks < 2; ks++) {
          pa[mb][ks].q[0] = make_uint2(cvtpk_bf16(p[2 * ks][0], p[2 * ks][1]),
                                       cvtpk_bf16(p[2 * ks][2], p[2 * ks][3]));
          pa[mb][ks].q[1] = make_uint2(cvtpk_bf16(p[2 * ks + 1][0], p[2 * ks + 1][1]),
                                       cvtpk_bf16(p[2 * ks + 1][2], p[2 * ks + 1][3]));
        }
      }

      #pragma unroll
      for (int ks = 0; ks < 2; ks++) {
        FragAB vf[4];
        #pragma unroll
        for (int nd = 0; nd < 4; nd++) {
          const u16* bb = &Vt[(nd * 16 + r) * 72 + ks * 32 + g * 4];
          vf[nd].q[0] = *(const uint2*)(bb);
          vf[nd].q[1] = *(const uint2*)(bb + 16);
        }
        __builtin_amdgcn_s_setprio(1);
        #pragma unroll
        for (int mb = 0; mb < 2; mb++)
          #pragma unroll
          for (int nd = 0; nd < 4; nd++)
            o[mb][nd] = __builtin_amdgcn_mfma_f32_16x16x32_bf16(vf[nd].v, pa[mb][ks].v, o[mb][nd], 0, 0, 0);
        __builtin_amdgcn_s_setprio(0);
      }
    }

    if (jt + 1 < nt) writet((jt & 1) ? Ks0 : Ks1, (jt & 1) ? Vt0 : Vt1);
    __syncthreads();   // one barrier per tile
  }

  u16* Og = O + ((size_t)(b * 2048 + base)) * 2048 + h * 64;
  #pragma unroll
  for (int mb = 0; mb < 2; mb++) {
    float inv = 1.f / l_run[mb];
    #pragma unroll
    for (int nd = 0; nd < 4; nd++) {
      ushort4 hv;
      hv.x = f2bf(o[mb][nd][0] * inv); hv.y = f2bf(o[mb][nd][1] * inv);
      hv.z = f2bf(o[mb][nd][2] * inv); hv.w = f2bf(o[mb][nd][3] * inv);
      *(ushort4*)(Og + (size_t)(mb * 16 + r) * 2048 + nd * 16 + g * 4) = hv;
    }
  }
}

extern "C" void kernel_launch(void* const* d_in, const int* in_sizes, int n_in,
                              void* d_out, int out_size, void* d_ws, size_t ws_size,
                              hipStream_t stream)
{
  (void)in_sizes; (void)n_in; (void)out_size; (void)ws_size;
  const float* X  = (const float*)d_in[0];
  const float* Wq = (const float*)d_in[1];
  const float* Wk = (const float*)d_in[2];
  const float* Wv = (const float*)d_in[3];
  const float* Wo = (const float*)d_in[4];
  float* out = (float*)d_out;

  u16* Xb  = (u16*)d_ws;                         // [4096][2048]
  u16* Qb  = Xb  + (size_t)NROW * HID;           // [4096][2048] (pre-scaled by SC2)
  u16* Kb  = Qb  + (size_t)NROW * HID;           // [4096][512]
  u16* VTb = Kb  + (size_t)NROW * KVH;           // [512][4096]  (V transposed)
  u16* Wqt = VTb + (size_t)NROW * KVH;           // [2048][2048]
  u16* Wkt = Wqt + (size_t)HID * HID;            // [512][2048]
  u16* Wvt = Wkt + (size_t)HID * KVH;
  u16* AOb = Xb;    // alias: X dead after KV gemm
  u16* Wot = Wqt;   // alias: Wqt dead after Q gemm

  conv_bf16<<<2048, 256, 0, stream>>>(X, Xb, NROW * HID / 4);
  transpose_conv<<<dim3(64, 64), dim3(32, 8), 0, stream>>>(Wq, Wqt, HID, HID);
  transpose_conv2<<<dim3(16, 64, 2), dim3(32, 8), 0, stream>>>(Wk, Wv, Wkt, Wvt, HID, KVH);
  gemm_bt<1, 0><<<dim3(16, 32), 256, 0, stream>>>(Xb, Wqt, Wqt, Qb, Qb, 16, HID, HID, SC2);
  gemm_bt<1, 1><<<dim3(8, 32), 256, 0, stream>>>(Xb, Wkt, Wvt, Kb, VTb, 4, KVH, HID, 1.f);
  transpose_conv<<<dim3(64, 64), dim3(32, 8), 0, stream>>>(Wo, Wot, HID, HID);
  attn_mfma<<<dim3(16, 32, 2), 256, 0, stream>>>(Qb, Kb, VTb, AOb);
  gemm_bt<0, 0><<<dim3(16, 32), 256, 0, stream>>>(AOb, Wot, Wot, out, out, 16, HID, HID, 1.f);
}

// Round 10
// 272.674 us; speedup vs baseline: 1.2765x; 1.1821x over previous
//
#include <hip/hip_runtime.h>

typedef unsigned short u16;
typedef unsigned int u32;
typedef __attribute__((ext_vector_type(8))) short short8_t;
typedef __attribute__((ext_vector_type(4))) float f32x4;

#define HID 2048
#define KVH 512
#define NROW 4096   // B*S
#define SC2 0.18033688011112042f   // (1/sqrt(64)) * log2(e)

__device__ __forceinline__ u16 f2bf(float f){
  u32 u = __builtin_bit_cast(u32, f);
  u += 0x7fffu + ((u >> 16) & 1u);   // round-to-nearest-even
  return (u16)(u >> 16);
}
__device__ __forceinline__ float bfu(u16 x){ return __builtin_bit_cast(float, (u32)x << 16); }
__device__ __forceinline__ u32 cvtpk_bf16(float lo, float hi){
  u32 r; asm("v_cvt_pk_bf16_f32 %0, %1, %2" : "=v"(r) : "v"(lo), "v"(hi)); return r;
}

union FragAB { short8_t v; uint4 u4; uint2 q[2]; };

__device__ __forceinline__ void gload_lds16(const u16* g, u16* l){
  __builtin_amdgcn_global_load_lds((const __attribute__((address_space(1))) void*)g,
                                   (__attribute__((address_space(3))) void*)l, 16, 0, 0);
}

// ---------- prep: fp32 -> bf16 convert ----------
__global__ __launch_bounds__(256)
void conv_bf16(const float* __restrict__ X, u16* __restrict__ Y, int n4)
{
  for (int i = blockIdx.x * 256 + threadIdx.x; i < n4; i += gridDim.x * 256) {
    float4 v = ((const float4*)X)[i];
    ushort4 h; h.x = f2bf(v.x); h.y = f2bf(v.y); h.z = f2bf(v.z); h.w = f2bf(v.w);
    ((ushort4*)Y)[i] = h;
  }
}

// ---------- prep: W[K][N] fp32 -> Wt[N][K] bf16 ----------
__global__ __launch_bounds__(256)
void transpose_conv(const float* __restrict__ W, u16* __restrict__ Wt, int K, int N)
{
  __shared__ float tile[32][33];
  int x = blockIdx.x * 32 + threadIdx.x;
  int y0 = blockIdx.y * 32;
  #pragma unroll
  for (int j = threadIdx.y; j < 32; j += 8)
    tile[j][threadIdx.x] = W[(size_t)(y0 + j) * N + x];
  __syncthreads();
  #pragma unroll
  for (int j = threadIdx.y; j < 32; j += 8)
    Wt[(size_t)(blockIdx.x * 32 + j) * K + y0 + threadIdx.x] = f2bf(tile[threadIdx.x][j]);
}

// two same-shape transposes in one launch (z selects)
__global__ __launch_bounds__(256)
void transpose_conv2(const float* __restrict__ W0, const float* __restrict__ W1,
                     u16* __restrict__ T0, u16* __restrict__ T1, int K, int N)
{
  __shared__ float tile[32][33];
  const float* W = blockIdx.z ? W1 : W0;
  u16* Wt = blockIdx.z ? T1 : T0;
  int x = blockIdx.x * 32 + threadIdx.x;
  int y0 = blockIdx.y * 32;
  #pragma unroll
  for (int j = threadIdx.y; j < 32; j += 8)
    tile[j][threadIdx.x] = W[(size_t)(y0 + j) * N + x];
  __syncthreads();
  #pragma unroll
  for (int j = threadIdx.y; j < 32; j += 8)
    Wt[(size_t)(blockIdx.x * 32 + j) * K + y0 + threadIdx.x] = f2bf(tile[threadIdx.x][j]);
}

// ---------- bf16 GEMM, B^T input (m97 structure) ----------
template<int CBF, int CT1>
__global__ __launch_bounds__(256)
void gemm_bt(const u16* __restrict__ A, const u16* __restrict__ B0,
             const u16* __restrict__ B1, void* __restrict__ C0,
             void* __restrict__ C1, int nsplit, int N, int K, float scale)
{
  __shared__ __align__(16) u16 As[128 * 64];
  __shared__ __align__(16) u16 Bs[128 * 64];
  const int t = threadIdx.x, lane = t & 63, wid = t >> 6;
  const int wm = wid >> 1, wn = wid & 1;
  const int r = lane & 15, g = lane >> 4;
  const u16* Bt; char* Cp; int n0;
  if ((int)blockIdx.x < nsplit) { Bt = B0; Cp = (char*)C0; n0 = blockIdx.x * 128; }
  else { Bt = B1; Cp = (char*)C1; n0 = ((int)blockIdx.x - nsplit) * 128; }
  const int m0 = blockIdx.y * 128;

  f32x4 acc[4][4];
  #pragma unroll
  for (int i = 0; i < 4; i++)
    #pragma unroll
    for (int j = 0; j < 4; j++) acc[i][j] = (f32x4){0.f, 0.f, 0.f, 0.f};

  const u16* Arow = A + (size_t)m0 * K;
  const u16* Brow = Bt + (size_t)n0 * K;
  const int lrow = t >> 3, lcol = (t & 7) * 8;

  for (int k0 = 0; k0 < K; k0 += 64) {
    __syncthreads();
    #pragma unroll
    for (int c = 0; c < 4; ++c) {
      gload_lds16(Arow + (size_t)(c * 32 + lrow) * K + k0 + lcol, As + c * 2048 + wid * 512);
      gload_lds16(Brow + (size_t)(c * 32 + lrow) * K + k0 + lcol, Bs + c * 2048 + wid * 512);
    }
    __syncthreads();
    #pragma unroll
    for (int kk = 0; kk < 64; kk += 32) {
      FragAB a[4], b[4];
      #pragma unroll
      for (int mi = 0; mi < 4; mi++)
        a[mi].u4 = *(const uint4*)&As[(wm * 64 + mi * 16 + r) * 64 + kk + g * 8];
      #pragma unroll
      for (int ni = 0; ni < 4; ni++)
        b[ni].u4 = *(const uint4*)&Bs[(wn * 64 + ni * 16 + r) * 64 + kk + g * 8];
      #pragma unroll
      for (int mi = 0; mi < 4; mi++)
        #pragma unroll
        for (int ni = 0; ni < 4; ni++)
          acc[mi][ni] = __builtin_amdgcn_mfma_f32_16x16x32_bf16(a[mi].v, b[ni].v, acc[mi][ni], 0, 0, 0);
    }
  }
  if (CT1 && (int)blockIdx.x >= nsplit) {
    u16* Ct = (u16*)Cp;
    #pragma unroll
    for (int mi = 0; mi < 4; mi++) {
      int row = m0 + wm * 64 + mi * 16 + g * 4;
      #pragma unroll
      for (int ni = 0; ni < 4; ni++) {
        int col = n0 + wn * 64 + ni * 16 + r;
        ushort4 hv;
        hv.x = f2bf(acc[mi][ni][0] * scale); hv.y = f2bf(acc[mi][ni][1] * scale);
        hv.z = f2bf(acc[mi][ni][2] * scale); hv.w = f2bf(acc[mi][ni][3] * scale);
        *(ushort4*)&Ct[(size_t)col * NROW + row] = hv;
      }
    }
  } else {
    #pragma unroll
    for (int mi = 0; mi < 4; mi++) {
      int row = m0 + wm * 64 + mi * 16 + g * 4;
      #pragma unroll
      for (int ni = 0; ni < 4; ni++) {
        int col = n0 + wn * 64 + ni * 16 + r;
        #pragma unroll
        for (int rr = 0; rr < 4; rr++) {
          if (CBF) ((u16*)Cp)[(size_t)(row + rr) * N + col] = f2bf(acc[mi][ni][rr] * scale);
          else     ((float*)Cp)[(size_t)(row + rr) * N + col] = acc[mi][ni][rr];
        }
      }
    }
  }
}

// ---------- MFMA flash attention, split-K partial (R5 structure) ----------
// One (qb, half) unit: tiles [t0,t1). Writes UNNORMALIZED partial o (bf16) and
// per-row (m,l) f32. Combine kernel merges the two halves.
__device__ __forceinline__ void attn_part(const u16* __restrict__ Q, const u16* __restrict__ K,
    const u16* __restrict__ VT, u16* __restrict__ Opart, float2* __restrict__ Ml,
    u16* Ks0, u16* Vt0, u16* Ks1, u16* Vt1, int qb, int half, int h, int b)
{
  const int t = threadIdx.x, lane = t & 63, w = t >> 6;
  const int r = lane & 15, g = lane >> 4;
  const int kvh = h >> 2;
  const int base = qb * 128 + w * 32;

  FragAB qf[2][2];
  {
    const u16* Qg = Q + ((size_t)(b * 2048 + base)) * 2048 + h * 64;
    #pragma unroll
    for (int mb = 0; mb < 2; mb++)
      #pragma unroll
      for (int ks = 0; ks < 2; ks++)
        qf[mb][ks].u4 = *(const uint4*)(Qg + (size_t)(mb * 16 + r) * 2048 + ks * 32 + g * 8);
  }

  float m_run[2] = {-1e30f, -1e30f}, l_run[2] = {0.f, 0.f};
  f32x4 o[2][4];
  #pragma unroll
  for (int mb = 0; mb < 2; mb++)
    #pragma unroll
    for (int nd = 0; nd < 4; nd++) o[mb][nd] = (f32x4){0.f, 0.f, 0.f, 0.f};

  const u16* Kg0 = K + (size_t)(b * 2048) * 512 + kvh * 64;
  const u16* Vg0 = VT + (size_t)(kvh * 64) * NROW + (size_t)b * 2048;
  const int t0 = half ? (qb + 1) : 0;
  const int t1 = half ? (2 * qb + 2) : (qb + 1);
  const int srow = t >> 3, scol = (t & 7) * 8;

  uint4 kr0, kr1, vr0, vr1;   // staging regs (issue-early / write-late)
  auto loadt = [&](int jt) {
    const u16* Kg = Kg0 + (size_t)(jt * 64) * 512;
    kr0 = *(const uint4*)(Kg + (size_t)srow * 512 + scol);
    kr1 = *(const uint4*)(Kg + (size_t)(srow + 32) * 512 + scol);
    const u16* Vg = Vg0 + jt * 64;
    vr0 = *(const uint4*)(Vg + (size_t)srow * NROW + scol);
    vr1 = *(const uint4*)(Vg + (size_t)(srow + 32) * NROW + scol);
  };
  auto writet = [&](u16* Ks, u16* Vt) {
    *(uint4*)&Ks[srow * 72 + scol] = kr0;
    *(uint4*)&Ks[(srow + 32) * 72 + scol] = kr1;
    *(uint4*)&Vt[srow * 72 + scol] = vr0;
    *(uint4*)&Vt[(srow + 32) * 72 + scol] = vr1;
  };

  loadt(t0);
  writet(Ks0, Vt0);
  __syncthreads();

  for (int jt = t0; jt < t1; ++jt) {
    const int jl = jt - t0;
    u16* Ks = (jl & 1) ? Ks1 : Ks0;
    u16* Vt = (jl & 1) ? Vt1 : Vt0;
    if (jt + 1 < t1) loadt(jt + 1);

    if (jt * 64 <= base + 31) {  // wave participates (causal)
      f32x4 st[2][4];
      #pragma unroll
      for (int mb = 0; mb < 2; mb++)
        #pragma unroll
        for (int kb = 0; kb < 4; kb++) st[mb][kb] = (f32x4){0.f, 0.f, 0.f, 0.f};
      #pragma unroll
      for (int ks = 0; ks < 2; ks++) {
        FragAB kf[4];
        #pragma unroll
        for (int kb = 0; kb < 4; kb++)
          kf[kb].u4 = *(const uint4*)&Ks[(kb * 16 + r) * 72 + ks * 32 + g * 8];
        __builtin_amdgcn_s_setprio(1);
        #pragma unroll
        for (int mb = 0; mb < 2; mb++)
          #pragma unroll
          for (int kb = 0; kb < 4; kb++)
            st[mb][kb] = __builtin_amdgcn_mfma_f32_16x16x32_bf16(kf[kb].v, qf[mb][ks].v, st[mb][kb], 0, 0, 0);
        __builtin_amdgcn_s_setprio(0);
      }

      FragAB pa[2][2];
      #pragma unroll
      for (int mb = 0; mb < 2; mb++) {
        const int rowg = base + mb * 16 + r;
        float sl[4][4];
        #pragma unroll
        for (int kb = 0; kb < 4; kb++)
          #pragma unroll
          for (int i = 0; i < 4; i++) sl[kb][i] = st[mb][kb][i];
        if (jt * 64 + 63 > base + mb * 16) {   // tile crosses diagonal
          const int kdel = jt * 64 + g * 4 - rowg;
          #pragma unroll
          for (int kb = 0; kb < 4; kb++)
            #pragma unroll
            for (int i = 0; i < 4; i++)
              if (kdel + kb * 16 + i > 0) sl[kb][i] = -1e30f;
        }
        float pm = sl[0][0];
        #pragma unroll
        for (int kb = 0; kb < 4; kb++)
          #pragma unroll
          for (int i = 0; i < 4; i++) pm = fmaxf(pm, sl[kb][i]);
        pm = fmaxf(pm, __shfl_xor(pm, 16));
        pm = fmaxf(pm, __shfl_xor(pm, 32));
        if (__any(pm > m_run[mb] + 8.f)) {   // defer-max rescale
          float mn = fmaxf(m_run[mb], pm);
          float corr = __builtin_exp2f(m_run[mb] - mn);
          m_run[mb] = mn;
          l_run[mb] *= corr;
          #pragma unroll
          for (int nd = 0; nd < 4; nd++)
            #pragma unroll
            for (int i = 0; i < 4; i++) o[mb][nd][i] *= corr;
        }
        float p[4][4]; float ls = 0.f;
        #pragma unroll
        for (int kb = 0; kb < 4; kb++)
          #pragma unroll
          for (int i = 0; i < 4; i++) { p[kb][i] = __builtin_exp2f(sl[kb][i] - m_run[mb]); ls += p[kb][i]; }
        ls += __shfl_xor(ls, 16);
        ls += __shfl_xor(ls, 32);
        l_run[mb] += ls;
        #pragma unroll
        for (int ks = 0; ks < 2; ks++) {
          pa[mb][ks].q[0] = make_uint2(cvtpk_bf16(p[2 * ks][0], p[2 * ks][1]),
                                       cvtpk_bf16(p[2 * ks][2], p[2 * ks][3]));
          pa[mb][ks].q[1] = make_uint2(cvtpk_bf16(p[2 * ks + 1][0], p[2 * ks + 1][1]),
                                       cvtpk_bf16(p[2 * ks + 1][2], p[2 * ks + 1][3]));
        }
      }

      #pragma unroll
      for (int ks = 0; ks < 2; ks++) {
        FragAB vf[4];
        #pragma unroll
        for (int nd = 0; nd < 4; nd++) {
          const u16* bb = &Vt[(nd * 16 + r) * 72 + ks * 32 + g * 4];
          vf[nd].q[0] = *(const uint2*)(bb);
          vf[nd].q[1] = *(const uint2*)(bb + 16);
        }
        __builtin_amdgcn_s_setprio(1);
        #pragma unroll
        for (int mb = 0; mb < 2; mb++)
          #pragma unroll
          for (int nd = 0; nd < 4; nd++)
            o[mb][nd] = __builtin_amdgcn_mfma_f32_16x16x32_bf16(vf[nd].v, pa[mb][ks].v, o[mb][nd], 0, 0, 0);
        __builtin_amdgcn_s_setprio(0);
      }
    }

    if (jt + 1 < t1) writet((jl & 1) ? Ks0 : Ks1, (jl & 1) ? Vt0 : Vt1);
    __syncthreads();   // one barrier per tile
  }

  // epilogue: UNNORMALIZED partial o (bf16) + per-row (m,l) once (g==0 lanes)
  u16* Og = Opart + ((size_t)(b * 2048 + base)) * 2048 + h * 64;
  #pragma unroll
  for (int mb = 0; mb < 2; mb++) {
    #pragma unroll
    for (int nd = 0; nd < 4; nd++) {
      ushort4 hv;
      hv.x = f2bf(o[mb][nd][0]); hv.y = f2bf(o[mb][nd][1]);
      hv.z = f2bf(o[mb][nd][2]); hv.w = f2bf(o[mb][nd][3]);
      *(ushort4*)(Og + (size_t)(mb * 16 + r) * 2048 + nd * 16 + g * 4) = hv;
    }
    if (g == 0) {
      int rowg = b * 2048 + base + mb * 16 + r;
      Ml[((size_t)half * NROW + rowg) * 32 + h] = make_float2(m_run[mb], l_run[mb]);
    }
  }
}

// Split-K pairs: block bx does (bx, half0) + (15-bx, half1) = (bx+1)+(16-bx) = 17 tiles.
// 1024 blocks -> 4 blocks/CU (LDS 147.5/160 KB, VGPR 4x~116/512 per SIMD).
__global__ __launch_bounds__(256)
void attn_mfma(const u16* __restrict__ Q, const u16* __restrict__ K,
               const u16* __restrict__ VT, u16* __restrict__ O0,
               u16* __restrict__ O1, float2* __restrict__ Ml)
{
  __shared__ __align__(16) u16 Ks0[64 * 72];
  __shared__ __align__(16) u16 Vt0[64 * 72];
  __shared__ __align__(16) u16 Ks1[64 * 72];
  __shared__ __align__(16) u16 Vt1[64 * 72];
  const int h = blockIdx.y, b = blockIdx.z, bx = blockIdx.x;
  attn_part(Q, K, VT, O1, Ml, Ks0, Vt0, Ks1, Vt1, 15 - bx, 1, h, b);
  attn_part(Q, K, VT, O0, Ml, Ks0, Vt0, Ks1, Vt1, bx, 0, h, b);
}

// merge the two KV-halves: O = (e0*o0 + e1*o1) / (e0*l0 + e1*l1), e_i = 2^(m_i - M)
__global__ __launch_bounds__(256)
void attn_combine(const u16* __restrict__ O0, const u16* __restrict__ O1,
                  const float2* __restrict__ Ml, u16* __restrict__ AO)
{
  int i = blockIdx.x * 256 + threadIdx.x;           // quad index, 2^21 total
  size_t e = (size_t)i * 4;
  int rowg = (int)(e >> 11), col = (int)(e & 2047), h = col >> 6;
  float2 ml0 = Ml[(size_t)rowg * 32 + h];
  float2 ml1 = Ml[((size_t)NROW + rowg) * 32 + h];
  float M = fmaxf(ml0.x, ml1.x);
  float e0 = __builtin_exp2f(ml0.x - M), e1 = __builtin_exp2f(ml1.x - M);
  float inv = 1.f / (e0 * ml0.y + e1 * ml1.y);
  ushort4 a = *(const ushort4*)&O0[e];
  ushort4 c = *(const ushort4*)&O1[e];
  ushort4 r;
  r.x = f2bf((bfu(a.x) * e0 + bfu(c.x) * e1) * inv);
  r.y = f2bf((bfu(a.y) * e0 + bfu(c.y) * e1) * inv);
  r.z = f2bf((bfu(a.z) * e0 + bfu(c.z) * e1) * inv);
  r.w = f2bf((bfu(a.w) * e0 + bfu(c.w) * e1) * inv);
  *(ushort4*)&AO[e] = r;
}

extern "C" void kernel_launch(void* const* d_in, const int* in_sizes, int n_in,
                              void* d_out, int out_size, void* d_ws, size_t ws_size,
                              hipStream_t stream)
{
  (void)in_sizes; (void)n_in; (void)out_size; (void)ws_size;
  const float* X  = (const float*)d_in[0];
  const float* Wq = (const float*)d_in[1];
  const float* Wk = (const float*)d_in[2];
  const float* Wv = (const float*)d_in[3];
  const float* Wo = (const float*)d_in[4];
  float* out = (float*)d_out;

  u16* Xb  = (u16*)d_ws;                         // [4096][2048]
  u16* Qb  = Xb  + (size_t)NROW * HID;           // [4096][2048] (pre-scaled by SC2)
  u16* Kb  = Qb  + (size_t)NROW * HID;           // [4096][512]
  u16* VTb = Kb  + (size_t)NROW * KVH;           // [512][4096]  (V transposed)
  u16* Wqt = VTb + (size_t)NROW * KVH;           // [2048][2048]
  u16* Wkt = Wqt + (size_t)HID * HID;            // [512][2048]
  u16* Wvt = Wkt + (size_t)HID * KVH;
  u16* Op0 = Wvt + (size_t)HID * KVH;            // [4096][2048] partial half0
  u16* Op1 = Op0 + (size_t)NROW * HID;           // [4096][2048] partial half1
  float2* Ml = (float2*)(Op1 + (size_t)NROW * HID);  // [2][4096][32]
  u16* AOb = Xb;    // alias: X dead after KV gemm
  u16* Wot = Wqt;   // alias: Wqt dead after Q gemm

  conv_bf16<<<2048, 256, 0, stream>>>(X, Xb, NROW * HID / 4);
  transpose_conv<<<dim3(64, 64), dim3(32, 8), 0, stream>>>(Wq, Wqt, HID, HID);
  transpose_conv2<<<dim3(16, 64, 2), dim3(32, 8), 0, stream>>>(Wk, Wv, Wkt, Wvt, HID, KVH);
  gemm_bt<1, 0><<<dim3(16, 32), 256, 0, stream>>>(Xb, Wqt, Wqt, Qb, Qb, 16, HID, HID, SC2);
  gemm_bt<1, 1><<<dim3(8, 32), 256, 0, stream>>>(Xb, Wkt, Wvt, Kb, VTb, 4, KVH, HID, 1.f);
  transpose_conv<<<dim3(64, 64), dim3(32, 8), 0, stream>>>(Wo, Wot, HID, HID);
  attn_mfma<<<dim3(16, 32, 2), 256, 0, stream>>>(Qb, Kb, VTb, Op0, Op1, Ml);
  attn_combine<<<NROW * HID / 4 / 256, 256, 0, stream>>>(Op0, Op1, Ml, AOb);
  gemm_bt<0, 0><<<dim3(16, 32), 256, 0, stream>>>(AOb, Wot, Wot, out, out, 16, HID, HID, 1.f);
}